// Round 1
// baseline (961.650 us; speedup 1.0000x reference)
//
#include <hip/hip_runtime.h>

#define BB   32
#define NN   512
#define NH   8
#define FIN  768
#define FHID 64
#define NROWS (BB*NN)   // 16384

__device__ __forceinline__ float lrelu_f(float s){ return s >= 0.f ? s : 0.2f*s; }
__device__ __forceinline__ float elu_f(float s){ return s > 0.f ? s : expm1f(s); }

// ---------------------------------------------------------------------------
// K1: adjacency -> bitmask words; node type -> per-type gathered row lists
// ---------------------------------------------------------------------------
__global__ __launch_bounds__(256) void prep_kernel(
    const int* __restrict__ adj, const float* __restrict__ vt,
    unsigned long long* __restrict__ maskw,
    int* __restrict__ rowlist, int* __restrict__ counts)
{
  int row  = blockIdx.x * 4 + (threadIdx.x >> 6);
  int lane = threadIdx.x & 63;
  const int* arow = adj + (long)row * NN;
  #pragma unroll
  for (int w = 0; w < 8; ++w) {
    unsigned long long bal = __ballot(arow[w*64 + lane] > 0);
    if (lane == 0) maskw[(long)row*8 + w] = bal;
  }
  if (lane == 0) {
    const float* v = vt + (long)row*3;
    int t = v[1] > 0.5f ? 1 : (v[2] > 0.5f ? 2 : 0);
    int pos = atomicAdd(&counts[t], 1);
    rowlist[t*NROWS + pos] = row;
  }
}

// ---------------------------------------------------------------------------
// K2/K5: gathered-row f32 GEMM.  C[row, colbase+0..63] = A[row,:] @ Bm[k,o]
// Bm = B0 + t*sBt + blockIdx.x*sBh, laid out [k][o] with o contiguous (64).
// tile 64 rows x 64 cols, K-step 16, 256 threads, 4x4 per-thread.
// ---------------------------------------------------------------------------
__global__ __launch_bounds__(256) void gat_gemm(
    const float* __restrict__ A, int lda,
    const float* __restrict__ B0, long sBt, long sBh, int K,
    const int* __restrict__ rowlist, const int* __restrict__ counts,
    float* __restrict__ C, int ldc)
{
  int t   = blockIdx.z;
  int cnt = counts[t];
  int r0  = blockIdx.y * 64;
  if (r0 >= cnt) return;
  const float* Bm = B0 + (long)t*sBt + (long)blockIdx.x*sBh;
  int colbase = blockIdx.x * 64;

  __shared__ float aS[16][68];   // [k][row], padded
  __shared__ float bS[16][64];   // [k][o]
  __shared__ int   rowsS[64];

  int tid = threadIdx.x;
  if (tid < 64) {
    int rr = r0 + tid;
    rowsS[tid] = (rr < cnt) ? rowlist[t*NROWS + rr] : -1;
  }
  __syncthreads();

  int tx = tid & 15, ty = tid >> 4;
  int la_row = tid >> 2, la_k = (tid & 3) * 4;
  int lb_k = tid >> 4,  lb_o = (tid & 15) * 4;
  int rowg = rowsS[la_row];
  const float* aptr = (rowg >= 0) ? (A + (long)rowg*lda) : nullptr;

  float acc[4][4] = {};
  for (int k0 = 0; k0 < K; k0 += 16) {
    float4 av = make_float4(0.f,0.f,0.f,0.f);
    if (aptr) av = *(const float4*)(aptr + k0 + la_k);
    float4 bv = *(const float4*)(Bm + (long)(k0 + lb_k)*64 + lb_o);
    __syncthreads();
    aS[la_k+0][la_row] = av.x;
    aS[la_k+1][la_row] = av.y;
    aS[la_k+2][la_row] = av.z;
    aS[la_k+3][la_row] = av.w;
    *(float4*)&bS[lb_k][lb_o] = bv;
    __syncthreads();
    #pragma unroll
    for (int kk = 0; kk < 16; ++kk) {
      float4 a4 = *(const float4*)&aS[kk][ty*4];
      float4 b4 = *(const float4*)&bS[kk][tx*4];
      float aa[4] = {a4.x, a4.y, a4.z, a4.w};
      float bb[4] = {b4.x, b4.y, b4.z, b4.w};
      #pragma unroll
      for (int i = 0; i < 4; ++i)
        #pragma unroll
        for (int j = 0; j < 4; ++j)
          acc[i][j] += aa[i]*bb[j];
    }
  }
  #pragma unroll
  for (int i = 0; i < 4; ++i) {
    int rr = ty*4 + i;
    int rg = rowsS[rr];
    if (r0 + rr < cnt && rg >= 0) {
      float4 v = make_float4(acc[i][0], acc[i][1], acc[i][2], acc[i][3]);
      *(float4*)(C + (long)rg*ldc + colbase + tx*4) = v;
    }
  }
}

// ---------------------------------------------------------------------------
// K3: GAT layer-1 attention, one workgroup per (b,h).  hp slice in LDS.
// Computes src/dst dots, masked softmax, PV; writes x = elu(out + b1) into
// x[b, n, h*64+o] (aliases hp1 storage: this block is the only reader/writer
// of exactly this region, and it is fully loaded to LDS before any write).
// ---------------------------------------------------------------------------
__global__ __launch_bounds__(256) void gat1_attn(
    const float* __restrict__ hp1, const unsigned long long* __restrict__ maskw,
    const float* __restrict__ a_src, const float* __restrict__ a_dst,
    const float* __restrict__ b1, float* __restrict__ xout)
{
  extern __shared__ float sm[];
  float* hpS  = sm;              // 512*64 = 32768
  float* srcS = hpS + 32768;     // 512
  float* dstS = srcS + 512;      // 512
  float* pS   = dstS + 512;      // 8*512 = 4096   (reduction scratch aliases)
  float* rcpS = pS + 4096;       // 8
  float4* hpS4 = (float4*)hpS;

  int b = blockIdx.x >> 3, h = blockIdx.x & 7;
  int tid = threadIdx.x;
  int og = tid & 15, m16 = tid >> 4;

  // load hp[b, :, h, :] -> LDS
  for (int it = 0; it < 32; ++it) {
    int fi = it*256 + tid;
    int m = fi >> 4, o4 = fi & 15;
    hpS4[m*16 + o4] = *(const float4*)(hp1 + ((long)(b*NN + m)*512 + h*64 + o4*4));
  }
  __syncthreads();

  // src/dst dots (16 lanes per row)
  float4 as4 = *(const float4*)(a_src + h*64 + og*4);
  float4 ad4 = *(const float4*)(a_dst + h*64 + og*4);
  for (int it = 0; it < 32; ++it) {
    int m = it*16 + m16;
    float4 hv = hpS4[m*16 + og];
    float ls = hv.x*as4.x + hv.y*as4.y + hv.z*as4.z + hv.w*as4.w;
    float ld = hv.x*ad4.x + hv.y*ad4.y + hv.z*ad4.z + hv.w*ad4.w;
    #pragma unroll
    for (int mk = 1; mk <= 8; mk <<= 1) {
      ls += __shfl_xor(ls, mk);
      ld += __shfl_xor(ld, mk);
    }
    if (og == 0) { srcS[m] = ls; dstS[m] = ld; }
  }

  int team = tid >> 5, lane32 = tid & 31;
  for (int c8 = 0; c8 < 64; ++c8) {
    __syncthreads();   // protects pS reuse (and first-iter src/dst visibility)
    int row = c8*8 + team;
    float srcv = srcS[row];
    const unsigned long long* mrow = maskw + (long)(b*NN + row)*8;

    float ev[16];
    float emax = -3.0e38f;
    #pragma unroll
    for (int j = 0; j < 16; ++j) {
      int m = j*32 + lane32;
      unsigned long long w = mrow[j >> 1];
      int bit = (int)((w >> (((j & 1) << 5) + lane32)) & 1ull);
      float s = srcv + dstS[m];
      float e = bit ? lrelu_f(s) : -1.0e9f;
      ev[j] = e;
      emax = fmaxf(emax, e);
    }
    #pragma unroll
    for (int mk = 1; mk <= 16; mk <<= 1) emax = fmaxf(emax, __shfl_xor(emax, mk));
    float lsum = 0.f;
    #pragma unroll
    for (int j = 0; j < 16; ++j) {
      float p = __expf(ev[j] - emax);
      lsum += p;
      pS[team*512 + j*32 + lane32] = p;
    }
    #pragma unroll
    for (int mk = 1; mk <= 16; mk <<= 1) lsum += __shfl_xor(lsum, mk);
    if (lane32 == 0) rcpS[team] = 1.f / lsum;
    __syncthreads();

    // PV: 16 o-quads x 16 m-groups, 8 rows per thread
    float4 acc[8];
    #pragma unroll
    for (int r = 0; r < 8; ++r) acc[r] = make_float4(0.f,0.f,0.f,0.f);
    for (int mm = 0; mm < 32; ++mm) {
      int m = mm*16 + m16;
      float4 hv = hpS4[m*16 + og];
      #pragma unroll
      for (int r = 0; r < 8; ++r) {
        float p = pS[r*512 + m];
        acc[r].x += hv.x*p; acc[r].y += hv.y*p;
        acc[r].z += hv.z*p; acc[r].w += hv.w*p;
      }
    }
    #pragma unroll
    for (int r = 0; r < 8; ++r) {
      acc[r].x += __shfl_xor(acc[r].x, 16); acc[r].y += __shfl_xor(acc[r].y, 16);
      acc[r].z += __shfl_xor(acc[r].z, 16); acc[r].w += __shfl_xor(acc[r].w, 16);
      acc[r].x += __shfl_xor(acc[r].x, 32); acc[r].y += __shfl_xor(acc[r].y, 32);
      acc[r].z += __shfl_xor(acc[r].z, 32); acc[r].w += __shfl_xor(acc[r].w, 32);
    }
    __syncthreads();                    // all PV reads of pS done
    int wv = tid >> 6, lane = tid & 63;
    if (lane < 16) {
      #pragma unroll
      for (int r = 0; r < 8; ++r)
        ((float4*)pS)[(wv*8 + r)*16 + lane] = acc[r];   // reduction scratch
    }
    __syncthreads();
    if (tid < 128) {
      int r = tid >> 4, o2 = tid & 15;
      float4 s = make_float4(0.f,0.f,0.f,0.f);
      #pragma unroll
      for (int w = 0; w < 4; ++w) {
        float4 v = ((float4*)pS)[(w*8 + r)*16 + o2];
        s.x += v.x; s.y += v.y; s.z += v.z; s.w += v.w;
      }
      float rc = rcpS[r];
      float4 bb = *(const float4*)(b1 + o2*4);
      float4 o;
      o.x = elu_f(s.x*rc + bb.x); o.y = elu_f(s.y*rc + bb.y);
      o.z = elu_f(s.z*rc + bb.z); o.w = elu_f(s.w*rc + bb.w);
      int rown = c8*8 + r;
      *(float4*)(xout + ((long)(b*NN + rown)*512 + h*64 + o2*4)) = o;
    }
  }
}

// ---------------------------------------------------------------------------
// K6: GAT layer-2 attention (rows 0,1 only) + ELU + MLP + log_softmax.
// One workgroup per batch element b.
// ---------------------------------------------------------------------------
__global__ __launch_bounds__(256) void gat2_final(
    const float* __restrict__ hp2, const unsigned long long* __restrict__ maskw,
    const float* __restrict__ a_src2, const float* __restrict__ a_dst2,
    const float* __restrict__ b2,
    const float* __restrict__ fc1_w, const float* __restrict__ fc1_b,
    const float* __restrict__ fc2_w, const float* __restrict__ fc2_b,
    const float* __restrict__ fc3_w, const float* __restrict__ fc3_b,
    float* __restrict__ out)
{
  extern __shared__ float sm[];
  float* hpS  = sm;              // 32768
  float* dstS = hpS + 32768;     // 512
  float* srcS = dstS + 512;      // 512
  float* pS   = srcS + 512;      // 512
  float* redS = pS + 512;        // 256 (4 waves x 16 og x float4)
  float* outS = redS + 256;      // 128 (2 rows x 64)
  float* vS   = outS + 128;      // 64
  float* y1S  = vS + 64;         // 192
  float* redM = y1S + 192;       // 8
  float4* hpS4 = (float4*)hpS;

  int b = blockIdx.x;
  int tid = threadIdx.x;
  int og = tid & 15, m16 = tid >> 4;

  for (int it = 0; it < 32; ++it) {
    int fi = it*256 + tid;
    int m = fi >> 4, o4 = fi & 15;
    hpS4[m*16 + o4] = *(const float4*)(hp2 + (long)(b*NN + m)*64 + o4*4);
  }
  __syncthreads();

  float4 as4 = *(const float4*)(a_src2 + og*4);
  float4 ad4 = *(const float4*)(a_dst2 + og*4);
  for (int it = 0; it < 32; ++it) {
    int m = it*16 + m16;
    float4 hv = hpS4[m*16 + og];
    float ls = hv.x*as4.x + hv.y*as4.y + hv.z*as4.z + hv.w*as4.w;
    float ld = hv.x*ad4.x + hv.y*ad4.y + hv.z*ad4.z + hv.w*ad4.w;
    #pragma unroll
    for (int mk = 1; mk <= 8; mk <<= 1) {
      ls += __shfl_xor(ls, mk);
      ld += __shfl_xor(ld, mk);
    }
    if (og == 0) { srcS[m] = ls; dstS[m] = ld; }
  }
  __syncthreads();

  for (int n = 0; n < 2; ++n) {
    float srcv = srcS[n];
    const unsigned long long* mrow = maskw + (long)(b*NN + n)*8;
    int m0 = tid, m1 = tid + 256;
    unsigned long long w0 = mrow[m0 >> 6], w1 = mrow[m1 >> 6];
    float s0 = srcv + dstS[m0], s1 = srcv + dstS[m1];
    float e0 = ((w0 >> (m0 & 63)) & 1ull) ? lrelu_f(s0) : -1.0e9f;
    float e1 = ((w1 >> (m1 & 63)) & 1ull) ? lrelu_f(s1) : -1.0e9f;
    float emax = fmaxf(e0, e1);
    #pragma unroll
    for (int mk = 1; mk <= 32; mk <<= 1) emax = fmaxf(emax, __shfl_xor(emax, mk));
    if ((tid & 63) == 0) redM[tid >> 6] = emax;
    __syncthreads();
    emax = fmaxf(fmaxf(redM[0], redM[1]), fmaxf(redM[2], redM[3]));
    float p0 = __expf(e0 - emax), p1 = __expf(e1 - emax);
    pS[m0] = p0; pS[m1] = p1;
    float lsum = p0 + p1;
    #pragma unroll
    for (int mk = 1; mk <= 32; mk <<= 1) lsum += __shfl_xor(lsum, mk);
    if ((tid & 63) == 0) redM[4 + (tid >> 6)] = lsum;
    __syncthreads();
    float rcp = 1.f / (redM[4] + redM[5] + redM[6] + redM[7]);

    float4 acc = make_float4(0.f,0.f,0.f,0.f);
    for (int mm = 0; mm < 32; ++mm) {
      int m = mm*16 + m16;
      float4 hv = hpS4[m*16 + og];
      float p = pS[m];
      acc.x += hv.x*p; acc.y += hv.y*p; acc.z += hv.z*p; acc.w += hv.w*p;
    }
    acc.x += __shfl_xor(acc.x, 16); acc.y += __shfl_xor(acc.y, 16);
    acc.z += __shfl_xor(acc.z, 16); acc.w += __shfl_xor(acc.w, 16);
    acc.x += __shfl_xor(acc.x, 32); acc.y += __shfl_xor(acc.y, 32);
    acc.z += __shfl_xor(acc.z, 32); acc.w += __shfl_xor(acc.w, 32);
    __syncthreads();
    if ((tid & 63) < 16) ((float4*)redS)[(tid >> 6)*16 + (tid & 15)] = acc;
    __syncthreads();
    if (tid < 16) {
      float4 s = make_float4(0.f,0.f,0.f,0.f);
      #pragma unroll
      for (int w = 0; w < 4; ++w) {
        float4 v = ((float4*)redS)[w*16 + tid];
        s.x += v.x; s.y += v.y; s.z += v.z; s.w += v.w;
      }
      float4 bb = *(const float4*)(b2 + tid*4);
      outS[n*64 + tid*4 + 0] = elu_f(s.x*rcp + bb.x);
      outS[n*64 + tid*4 + 1] = elu_f(s.y*rcp + bb.y);
      outS[n*64 + tid*4 + 2] = elu_f(s.z*rcp + bb.z);
      outS[n*64 + tid*4 + 3] = elu_f(s.w*rcp + bb.w);
    }
    __syncthreads();
  }

  // MLP
  if (tid < 64) vS[tid] = outS[tid] * outS[64 + tid];
  __syncthreads();
  if (tid < 192) {
    float a = fc1_b[tid];
    for (int o = 0; o < 64; ++o) a += vS[o]*fc1_w[o*192 + tid];
    y1S[tid] = a > 0.f ? a : 0.f;
  }
  __syncthreads();
  if (tid < 64) {
    float a = fc2_b[tid];
    for (int j = 0; j < 192; ++j) a += y1S[j]*fc2_w[j*64 + tid];
    vS[tid] = a > 0.f ? a : 0.f;   // reuse vS as y2
  }
  __syncthreads();
  if (tid == 0) {
    float t0 = fc3_b[0], t1 = fc3_b[1];
    for (int k = 0; k < 64; ++k) {
      float y = vS[k];
      t0 += y*fc3_w[k*2 + 0];
      t1 += y*fc3_w[k*2 + 1];
    }
    float mx = fmaxf(t0, t1);
    float lse = mx + logf(__expf(t0 - mx) + __expf(t1 - mx));
    out[b*2 + 0] = t0 - lse;
    out[b*2 + 1] = t1 - lse;
  }
}

// ---------------------------------------------------------------------------
extern "C" void kernel_launch(void* const* d_in, const int* in_sizes, int n_in,
                              void* d_out, int out_size, void* d_ws, size_t ws_size,
                              hipStream_t stream) {
  const float* emb    = (const float*)d_in[0];
  const int*   adj    = (const int*)d_in[1];
  const float* vt     = (const float*)d_in[2];
  const float* w1     = (const float*)d_in[3];
  const float* a_src1 = (const float*)d_in[4];
  const float* a_dst1 = (const float*)d_in[5];
  const float* b1     = (const float*)d_in[6];
  const float* w2     = (const float*)d_in[7];
  const float* a_src2 = (const float*)d_in[8];
  const float* a_dst2 = (const float*)d_in[9];
  const float* b2     = (const float*)d_in[10];
  const float* fc1_w  = (const float*)d_in[11];
  const float* fc1_b  = (const float*)d_in[12];
  const float* fc2_w  = (const float*)d_in[13];
  const float* fc2_b  = (const float*)d_in[14];
  const float* fc3_w  = (const float*)d_in[15];
  const float* fc3_b  = (const float*)d_in[16];

  char* ws = (char*)d_ws;
  int* counts  = (int*)ws;                                   // 16 B
  int* rowlist = (int*)(ws + 4096);                          // 3*16384*4
  unsigned long long* maskw = (unsigned long long*)(ws + 204800);  // 1 MB
  float* hp1 = (float*)(ws + 204800 + 1048576);              // 33.55 MB (aliased as x)
  float* hp2 = (float*)(ws + 204800 + 1048576 + (size_t)NROWS*512*4); // 4.19 MB
  float* xbuf = hp1;

  hipMemsetAsync(counts, 0, 16, stream);
  prep_kernel<<<NROWS/4, 256, 0, stream>>>(adj, vt, maskw, rowlist, counts);

  // layer 1 transform: K=768, col blocks = 8 heads
  gat_gemm<<<dim3(8, 256, 3), 256, 0, stream>>>(
      emb, FIN, w1, (long)NH*FIN*FHID, (long)FIN*FHID, FIN,
      rowlist, counts, hp1, 512);

  size_t sm1 = (size_t)(32768 + 512 + 512 + 4096 + 8) * 4;
  gat1_attn<<<BB*NH, 256, sm1, stream>>>(hp1, maskw, a_src1, a_dst1, b1, xbuf);

  // layer 2 transform: K=512, single 64-col block
  gat_gemm<<<dim3(1, 256, 3), 256, 0, stream>>>(
      xbuf, 512, w2, (long)512*64, 0, 512,
      rowlist, counts, hp2, 64);

  size_t sm2 = (size_t)(32768 + 512 + 512 + 512 + 256 + 128 + 64 + 192 + 8) * 4;
  gat2_final<<<BB, 256, sm2, stream>>>(hp2, maskw, a_src2, a_dst2, b2,
                                       fc1_w, fc1_b, fc2_w, fc2_b, fc3_w, fc3_b,
                                       (float*)d_out);
}